// Round 1
// baseline (3094.804 us; speedup 1.0000x reference)
//
#include <hip/hip_runtime.h>
#include <math.h>

// ---------------- degree accumulation ----------------
__global__ void degree_kernel(const int* __restrict__ src, const int* __restrict__ dst,
                              float* __restrict__ deg_out, float* __restrict__ deg_in, int E) {
    int gid = blockIdx.x * blockDim.x + threadIdx.x;
    if (gid < E) {
        atomicAdd(&deg_out[src[gid]], 1.0f);
        atomicAdd(&deg_in[dst[gid]], 1.0f);
    }
}

// ---------------- norm = rsqrt(max(deg,1)) in place ----------------
__global__ void norm_kernel(float* __restrict__ deg_out, float* __restrict__ deg_in, int N) {
    int gid = blockIdx.x * blockDim.x + threadIdx.x;
    if (gid < N) {
        deg_out[gid] = rsqrtf(fmaxf(deg_out[gid], 1.0f));
        deg_in[gid]  = rsqrtf(fmaxf(deg_in[gid], 1.0f));
    }
}

// ---------------- X = (H @ W) * norm_row  ----------------
// Tile: 64 nodes x 64 cols per 256-thread block; each thread 4 nodes x 4 cols.
// LDS: W natural [K][64]; H transposed [K][64] with row stride 68 (16B-aligned,
// bank-conflict-free b128 reads).
template<int K>
__global__ __launch_bounds__(256) void gemm_norm(const float* __restrict__ H,
                                                 const float* __restrict__ W,
                                                 const float* __restrict__ norm,
                                                 float* __restrict__ X, int N) {
    constexpr int KSHIFT = (K == 128) ? 7 : 6;
    __shared__ __align__(16) float sHT[K * 68];
    __shared__ __align__(16) float sW[K * 64];
    const int tid = threadIdx.x;
    const int n0 = blockIdx.x * 64;

    for (int i = tid; i < K * 64; i += 256) sW[i] = W[i];
    for (int i = tid; i < 64 * K; i += 256) {
        int n = i >> KSHIFT;
        int k = i & (K - 1);
        float v = (n0 + n < N) ? H[(size_t)(n0 + n) * K + k] : 0.0f;
        sHT[k * 68 + n] = v;
    }
    __syncthreads();

    const int tx = tid & 15;   // col group: cols 4*tx .. 4*tx+3
    const int ty = tid >> 4;   // node group: nodes 4*ty .. 4*ty+3
    float acc[4][4];
#pragma unroll
    for (int i = 0; i < 4; ++i)
#pragma unroll
        for (int m = 0; m < 4; ++m) acc[i][m] = 0.0f;

#pragma unroll 4
    for (int k = 0; k < K; ++k) {
        const float4 hv = *(const float4*)&sHT[k * 68 + 4 * ty];
        const float4 wv = *(const float4*)&sW[k * 64 + 4 * tx];
        acc[0][0] += hv.x * wv.x; acc[0][1] += hv.x * wv.y; acc[0][2] += hv.x * wv.z; acc[0][3] += hv.x * wv.w;
        acc[1][0] += hv.y * wv.x; acc[1][1] += hv.y * wv.y; acc[1][2] += hv.y * wv.z; acc[1][3] += hv.y * wv.w;
        acc[2][0] += hv.z * wv.x; acc[2][1] += hv.z * wv.y; acc[2][2] += hv.z * wv.z; acc[2][3] += hv.z * wv.w;
        acc[3][0] += hv.w * wv.x; acc[3][1] += hv.w * wv.y; acc[3][2] += hv.w * wv.z; acc[3][3] += hv.w * wv.w;
    }

#pragma unroll
    for (int i = 0; i < 4; ++i) {
        int n = n0 + 4 * ty + i;
        if (n < N) {
            float s = norm[n];
            float4 o;
            o.x = acc[i][0] * s; o.y = acc[i][1] * s; o.z = acc[i][2] * s; o.w = acc[i][3] * s;
            *(float4*)&X[(size_t)n * 64 + 4 * tx] = o;
        }
    }
}

// ---------------- edge aggregation: AGG[dst] += X[src] ----------------
// 16 threads per edge, float4 per thread (64 features).
__global__ void aggregate_kernel(const float* __restrict__ X, const int* __restrict__ src,
                                 const int* __restrict__ dst, float* __restrict__ AGG, int E) {
    int gid = blockIdx.x * blockDim.x + threadIdx.x;
    int e = gid >> 4;
    if (e >= E) return;
    int f = (gid & 15) * 4;
    int s = src[e];
    int d = dst[e];
    const float4 v = *(const float4*)(X + (size_t)s * 64 + f);
    float* p = AGG + (size_t)d * 64 + f;
    atomicAdd(p + 0, v.x);
    atomicAdd(p + 1, v.y);
    atomicAdd(p + 2, v.z);
    atomicAdd(p + 3, v.w);
}

// ---------------- A = act(A * norm_dst[n] + b[j]) in place ----------------
template<bool ELU>
__global__ void bias_act_kernel(float* __restrict__ A, const float* __restrict__ norm,
                                const float* __restrict__ b, int N) {
    int gid = blockIdx.x * blockDim.x + threadIdx.x;  // one float4 per thread
    if (gid < N * 16) {
        int n = gid >> 4;
        int jg = gid & 15;
        float4 a = ((const float4*)A)[gid];
        float s = norm[n];
        const float4 bb = ((const float4*)b)[jg];
        float4 r;
        r.x = a.x * s + bb.x;
        r.y = a.y * s + bb.y;
        r.z = a.z * s + bb.z;
        r.w = a.w * s + bb.w;
        if (ELU) {
            r.x = r.x > 0.0f ? r.x : expm1f(r.x);
            r.y = r.y > 0.0f ? r.y : expm1f(r.y);
            r.z = r.z > 0.0f ? r.z : expm1f(r.z);
            r.w = r.w > 0.0f ? r.w : expm1f(r.w);
        }
        ((float4*)A)[gid] = r;
    }
}

extern "C" void kernel_launch(void* const* d_in, const int* in_sizes, int n_in,
                              void* d_out, int out_size, void* d_ws, size_t ws_size,
                              hipStream_t stream) {
    const float* h   = (const float*)d_in[0];
    const int*   src = (const int*)d_in[1];
    const int*   dst = (const int*)d_in[2];
    const float* W1  = (const float*)d_in[3];
    const float* b1  = (const float*)d_in[4];
    const float* W2  = (const float*)d_in[5];
    const float* b2  = (const float*)d_in[6];
    float* out = (float*)d_out;

    const int N = in_sizes[0] / 128;   // 100000
    const int E = in_sizes[1];         // 1600000

    // workspace layout (floats): [norm_src N][norm_dst N][X 64N][AGG 64N]
    float* ws       = (float*)d_ws;
    float* norm_src = ws;
    float* norm_dst = ws + N;
    float* X        = ws + 2 * (size_t)N;
    float* AGG      = X + 64 * (size_t)N;

    // zero the accumulators (ws/d_out are poisoned 0xAA before every call)
    hipMemsetAsync(norm_src, 0, 2 * (size_t)N * sizeof(float), stream);
    hipMemsetAsync(AGG, 0, 64 * (size_t)N * sizeof(float), stream);
    hipMemsetAsync(out, 0, 64 * (size_t)N * sizeof(float), stream);

    degree_kernel<<<(E + 255) / 256, 256, 0, stream>>>(src, dst, norm_src, norm_dst, E);
    norm_kernel<<<(N + 255) / 256, 256, 0, stream>>>(norm_src, norm_dst, N);

    // layer 1: X = (h @ W1) * norm_src ; AGG = scatter-sum ; h1 = elu(AGG*norm_dst + b1)
    gemm_norm<128><<<(N + 63) / 64, 256, 0, stream>>>(h, W1, norm_src, X, N);
    {
        long long total = (long long)E * 16;
        aggregate_kernel<<<(unsigned)((total + 255) / 256), 256, 0, stream>>>(X, src, dst, AGG, E);
    }
    bias_act_kernel<true><<<(N * 16 + 255) / 256, 256, 0, stream>>>(AGG, norm_dst, b1, N);

    // layer 2: X = (h1 @ W2) * norm_src ; out = scatter-sum ; out = out*norm_dst + b2
    gemm_norm<64><<<(N + 63) / 64, 256, 0, stream>>>(AGG, W2, norm_src, X, N);
    {
        long long total = (long long)E * 16;
        aggregate_kernel<<<(unsigned)((total + 255) / 256), 256, 0, stream>>>(X, src, dst, out, E);
    }
    bias_act_kernel<false><<<(N * 16 + 255) / 256, 256, 0, stream>>>(out, norm_dst, b2, N);
}

// Round 2
// 614.114 us; speedup vs baseline: 5.0395x; 5.0395x over previous
//
#include <hip/hip_runtime.h>
#include <math.h>

// ---------------- degree histogram (int atomics, L2-resident counters) ----------------
__global__ void hist_kernel(const int* __restrict__ src, const int* __restrict__ dst,
                            int* __restrict__ cnt_out, int* __restrict__ cnt_in, int E) {
    int gid = blockIdx.x * blockDim.x + threadIdx.x;
    if (gid < E) {
        atomicAdd(&cnt_out[src[gid]], 1);
        atomicAdd(&cnt_in[dst[gid]], 1);
    }
}

// ---------------- norms from integer degrees ----------------
__global__ void norm_kernel(const int* __restrict__ cnt_out, const int* __restrict__ cnt_in,
                            float* __restrict__ norm_src, float* __restrict__ norm_dst, int N) {
    int gid = blockIdx.x * blockDim.x + threadIdx.x;
    if (gid < N) {
        norm_src[gid] = rsqrtf(fmaxf((float)cnt_out[gid], 1.0f));
        norm_dst[gid] = rsqrtf(fmaxf((float)cnt_in[gid], 1.0f));
    }
}

// ---------------- exclusive scan of cnt_in -> seg (3-phase) ----------------
// phase 1: per-block (1024 elems) local exclusive scan + block totals
__global__ __launch_bounds__(256) void scan1_kernel(const int* __restrict__ cnt,
                                                    int* __restrict__ seg,
                                                    int* __restrict__ bsums, int N) {
    __shared__ int tsum[256];
    const int t = threadIdx.x;
    const int base = blockIdx.x * 1024 + t * 4;
    int v0 = (base + 0 < N) ? cnt[base + 0] : 0;
    int v1 = (base + 1 < N) ? cnt[base + 1] : 0;
    int v2 = (base + 2 < N) ? cnt[base + 2] : 0;
    int v3 = (base + 3 < N) ? cnt[base + 3] : 0;
    tsum[t] = v0 + v1 + v2 + v3;
    __syncthreads();
    for (int off = 1; off < 256; off <<= 1) {
        int x = (t >= off) ? tsum[t - off] : 0;
        __syncthreads();
        if (t >= off) tsum[t] += x;
        __syncthreads();
    }
    int run = (t > 0) ? tsum[t - 1] : 0;
    if (base + 0 < N) seg[base + 0] = run; run += v0;
    if (base + 1 < N) seg[base + 1] = run; run += v1;
    if (base + 2 < N) seg[base + 2] = run; run += v2;
    if (base + 3 < N) seg[base + 3] = run;
    if (t == 255) bsums[blockIdx.x] = tsum[255];
}

// phase 2: scan block totals (G <= 256), write grand total to seg[N]
__global__ void scan2_kernel(int* __restrict__ bsums, int* __restrict__ seg, int N, int G) {
    __shared__ int s[256];
    int t = threadIdx.x;
    if (t < G) s[t] = bsums[t];
    __syncthreads();
    if (t == 0) {
        int run = 0;
        for (int i = 0; i < G; ++i) { int v = s[i]; s[i] = run; run += v; }
        seg[N] = run;
    }
    __syncthreads();
    if (t < G) bsums[t] = s[t];
}

// phase 3: add block offsets; also initialize cursor = seg
__global__ __launch_bounds__(256) void scan3_kernel(int* __restrict__ seg, int* __restrict__ cursor,
                                                    const int* __restrict__ bsums, int N) {
    int add = bsums[blockIdx.x];
    int base = blockIdx.x * 1024 + threadIdx.x * 4;
#pragma unroll
    for (int i = 0; i < 4; ++i) {
        int idx = base + i;
        if (idx < N) {
            int v = seg[idx] + add;
            seg[idx] = v;
            cursor[idx] = v;
        }
    }
}

// ---------------- scatter: CSR edge list sorted by dst ----------------
__global__ void scatter_kernel(const int* __restrict__ src, const int* __restrict__ dst,
                               int* __restrict__ cursor, int* __restrict__ esrc, int E) {
    int gid = blockIdx.x * blockDim.x + threadIdx.x;
    if (gid < E) {
        int p = atomicAdd(&cursor[dst[gid]], 1);
        esrc[p] = src[gid];
    }
}

// ---------------- X = (H @ W) * norm_row ----------------
template<int K>
__global__ __launch_bounds__(256) void gemm_norm(const float* __restrict__ H,
                                                 const float* __restrict__ W,
                                                 const float* __restrict__ norm,
                                                 float* __restrict__ X, int N) {
    constexpr int KSHIFT = (K == 128) ? 7 : 6;
    __shared__ __align__(16) float sHT[K * 68];
    __shared__ __align__(16) float sW[K * 64];
    const int tid = threadIdx.x;
    const int n0 = blockIdx.x * 64;

    for (int i = tid; i < K * 64; i += 256) sW[i] = W[i];
    for (int i = tid; i < 64 * K; i += 256) {
        int n = i >> KSHIFT;
        int k = i & (K - 1);
        float v = (n0 + n < N) ? H[(size_t)(n0 + n) * K + k] : 0.0f;
        sHT[k * 68 + n] = v;
    }
    __syncthreads();

    const int tx = tid & 15;
    const int ty = tid >> 4;
    float acc[4][4];
#pragma unroll
    for (int i = 0; i < 4; ++i)
#pragma unroll
        for (int m = 0; m < 4; ++m) acc[i][m] = 0.0f;

#pragma unroll 4
    for (int k = 0; k < K; ++k) {
        const float4 hv = *(const float4*)&sHT[k * 68 + 4 * ty];
        const float4 wv = *(const float4*)&sW[k * 64 + 4 * tx];
        acc[0][0] += hv.x * wv.x; acc[0][1] += hv.x * wv.y; acc[0][2] += hv.x * wv.z; acc[0][3] += hv.x * wv.w;
        acc[1][0] += hv.y * wv.x; acc[1][1] += hv.y * wv.y; acc[1][2] += hv.y * wv.z; acc[1][3] += hv.y * wv.w;
        acc[2][0] += hv.z * wv.x; acc[2][1] += hv.z * wv.y; acc[2][2] += hv.z * wv.z; acc[2][3] += hv.z * wv.w;
        acc[3][0] += hv.w * wv.x; acc[3][1] += hv.w * wv.y; acc[3][2] += hv.w * wv.z; acc[3][3] += hv.w * wv.w;
    }

#pragma unroll
    for (int i = 0; i < 4; ++i) {
        int n = n0 + 4 * ty + i;
        if (n < N) {
            float s = norm[n];
            float4 o;
            o.x = acc[i][0] * s; o.y = acc[i][1] * s; o.z = acc[i][2] * s; o.w = acc[i][3] * s;
            *(float4*)&X[(size_t)n * 64 + 4 * tx] = o;
        }
    }
}

// ---------------- segment sum over CSR + fused epilogue ----------------
// one wave per node, lane = feature; out = act(sum(X[esrc]) * norm_dst + b)
template<bool ELU>
__global__ __launch_bounds__(256) void segsum_kernel(const float* __restrict__ X,
                                                     const int* __restrict__ esrc,
                                                     const int* __restrict__ seg,
                                                     const float* __restrict__ norm_dst,
                                                     const float* __restrict__ b,
                                                     float* __restrict__ out, int N) {
    const int node = blockIdx.x * 4 + (threadIdx.x >> 6);
    const int lane = threadIdx.x & 63;
    if (node >= N) return;
    const int s0 = seg[node];
    const int s1 = seg[node + 1];
    float acc = 0.0f;
    int e = s0;
    for (; e + 4 <= s1; e += 4) {
        int a0 = esrc[e + 0];
        int a1 = esrc[e + 1];
        int a2 = esrc[e + 2];
        int a3 = esrc[e + 3];
        acc += X[(size_t)a0 * 64 + lane];
        acc += X[(size_t)a1 * 64 + lane];
        acc += X[(size_t)a2 * 64 + lane];
        acc += X[(size_t)a3 * 64 + lane];
    }
    for (; e < s1; ++e) acc += X[(size_t)esrc[e] * 64 + lane];
    float r = acc * norm_dst[node] + b[lane];
    if (ELU) r = (r > 0.0f) ? r : expm1f(r);
    out[(size_t)node * 64 + lane] = r;
}

extern "C" void kernel_launch(void* const* d_in, const int* in_sizes, int n_in,
                              void* d_out, int out_size, void* d_ws, size_t ws_size,
                              hipStream_t stream) {
    const float* h   = (const float*)d_in[0];
    const int*   src = (const int*)d_in[1];
    const int*   dst = (const int*)d_in[2];
    const float* W1  = (const float*)d_in[3];
    const float* b1  = (const float*)d_in[4];
    const float* W2  = (const float*)d_in[5];
    const float* b2  = (const float*)d_in[6];
    float* out = (float*)d_out;

    const int N = in_sizes[0] / 128;   // 100000
    const int E = in_sizes[1];         // 1600000

    // ---- workspace layout ----
    // ints:  cnt_out[N] cnt_in[N] seg[N+1] (pad 3) cursor[N] bsums[256] esrc[E]
    // floats: norm_src[N] norm_dst[N] X[64N] H1[64N]
    int* iw = (int*)d_ws;
    int* cnt_out = iw;
    int* cnt_in  = iw + (size_t)N;
    int* seg     = iw + 2 * (size_t)N;            // N+1 entries
    int* cursor  = iw + 3 * (size_t)N + 4;
    int* bsums   = iw + 4 * (size_t)N + 4;        // 256 entries
    int* esrc    = iw + 4 * (size_t)N + 260;
    float* fw       = (float*)(iw + 4 * (size_t)N + 260 + (size_t)E);
    float* norm_src = fw;
    float* norm_dst = fw + (size_t)N;
    float* X        = fw + 2 * (size_t)N;
    float* H1       = fw + 2 * (size_t)N + 64 * (size_t)N;

    hipMemsetAsync(cnt_out, 0, 2 * (size_t)N * sizeof(int), stream);

    // ---- CSR build (once; reused by both layers) ----
    hist_kernel<<<(E + 255) / 256, 256, 0, stream>>>(src, dst, cnt_out, cnt_in, E);
    norm_kernel<<<(N + 255) / 256, 256, 0, stream>>>(cnt_out, cnt_in, norm_src, norm_dst, N);
    const int G = (N + 1023) / 1024;  // 98 for N=100000 (<=256 required)
    scan1_kernel<<<G, 256, 0, stream>>>(cnt_in, seg, bsums, N);
    scan2_kernel<<<1, 256, 0, stream>>>(bsums, seg, N, G);
    scan3_kernel<<<G, 256, 0, stream>>>(seg, cursor, bsums, N);
    scatter_kernel<<<(E + 255) / 256, 256, 0, stream>>>(src, dst, cursor, esrc, E);

    // ---- layer 1 ----
    gemm_norm<128><<<(N + 63) / 64, 256, 0, stream>>>(h, W1, norm_src, X, N);
    segsum_kernel<true><<<(N + 3) / 4, 256, 0, stream>>>(X, esrc, seg, norm_dst, b1, H1, N);

    // ---- layer 2 ----
    gemm_norm<64><<<(N + 63) / 64, 256, 0, stream>>>(H1, W2, norm_src, X, N);
    segsum_kernel<false><<<(N + 3) / 4, 256, 0, stream>>>(X, esrc, seg, norm_dst, b2, out, N);
}

// Round 3
// 443.950 us; speedup vs baseline: 6.9711x; 1.3833x over previous
//
#include <hip/hip_runtime.h>
#include <math.h>

#define CH 4096        // edges per partition block
#define NBUK_MAX 256   // max buckets (N <= 131072)
#define MAXB 12288     // max edges per bucket staged in LDS (48 KB)

// ---------------- P1a: per-block bucket histograms (dst-bucket and src-bucket) ----------------
__global__ __launch_bounds__(256) void p1a_kernel(const int* __restrict__ src, const int* __restrict__ dst,
                                                  int* __restrict__ mat, int E, int B1, int nbuk) {
    __shared__ int hd[NBUK_MAX], hs[NBUK_MAX];
    const int t = threadIdx.x;
    if (t < nbuk) { hd[t] = 0; hs[t] = 0; }
    __syncthreads();
    const int base = blockIdx.x * CH;
    const int cnt = min(CH, E - base);
    for (int k = t; k < cnt; k += 256) {
        int d = dst[base + k];
        int s = src[base + k];
        atomicAdd(&hd[d >> 9], 1);
        atomicAdd(&hs[s >> 9], 1);
    }
    __syncthreads();
    if (t < nbuk) {
        mat[t * B1 + blockIdx.x] = hd[t];
        mat[(nbuk + t) * B1 + blockIdx.x] = hs[t];
    }
}

// ---------------- 3-phase exclusive scan (N up to 262144) ----------------
__global__ __launch_bounds__(256) void scan1_kernel(const int* __restrict__ cnt,
                                                    int* __restrict__ seg,
                                                    int* __restrict__ bsums, int N) {
    __shared__ int tsum[256];
    const int t = threadIdx.x;
    const int base = blockIdx.x * 1024 + t * 4;
    int v0 = (base + 0 < N) ? cnt[base + 0] : 0;
    int v1 = (base + 1 < N) ? cnt[base + 1] : 0;
    int v2 = (base + 2 < N) ? cnt[base + 2] : 0;
    int v3 = (base + 3 < N) ? cnt[base + 3] : 0;
    tsum[t] = v0 + v1 + v2 + v3;
    __syncthreads();
    for (int off = 1; off < 256; off <<= 1) {
        int x = (t >= off) ? tsum[t - off] : 0;
        __syncthreads();
        if (t >= off) tsum[t] += x;
        __syncthreads();
    }
    int run = (t > 0) ? tsum[t - 1] : 0;
    if (base + 0 < N) seg[base + 0] = run; run += v0;
    if (base + 1 < N) seg[base + 1] = run; run += v1;
    if (base + 2 < N) seg[base + 2] = run; run += v2;
    if (base + 3 < N) seg[base + 3] = run;
    if (t == 255) bsums[blockIdx.x] = tsum[255];
}

__global__ void scan2_kernel(int* __restrict__ bsums, int* __restrict__ seg, int N, int G) {
    __shared__ int s[256];
    int t = threadIdx.x;
    if (t < G) s[t] = bsums[t];
    __syncthreads();
    if (t == 0) {
        int run = 0;
        for (int i = 0; i < G; ++i) { int v = s[i]; s[i] = run; run += v; }
        seg[N] = run;
    }
    __syncthreads();
    if (t < G) bsums[t] = s[t];
}

__global__ __launch_bounds__(256) void scan3_kernel(int* __restrict__ seg,
                                                    const int* __restrict__ bsums, int N) {
    int add = bsums[blockIdx.x];
    int base = blockIdx.x * 1024 + threadIdx.x * 4;
#pragma unroll
    for (int i = 0; i < 4; ++i) {
        int idx = base + i;
        if (idx < N) seg[idx] += add;
    }
}

// ---------------- P1c: LDS-staged partition scatter ----------------
// Partitions (dst,src) by dst-bucket into pd/psqs[0..E) and src by src-bucket
// into psqs[E..2E) (the concatenated scan's matS values already include +E).
__global__ __launch_bounds__(256) void p1c_kernel(const int* __restrict__ src, const int* __restrict__ dst,
                                                  const int* __restrict__ scan,
                                                  int* __restrict__ pd, int* __restrict__ psqs,
                                                  int E, int B1, int nbuk) {
    __shared__ int hd[NBUK_MAX], hs[NBUK_MAX];       // inclusive scans after phase 2
    __shared__ int curD[NBUK_MAX], curS[NBUK_MAX];
    __shared__ int baseD[NBUK_MAX], baseS[NBUK_MAX];
    __shared__ int stD_d[CH];
    __shared__ int stD_s[CH];
    __shared__ int stS_s[CH];
    const int t = threadIdx.x;
    if (t < nbuk) { hd[t] = 0; hs[t] = 0; }
    __syncthreads();
    const int base = blockIdx.x * CH;
    const int cnt = min(CH, E - base);
    int dl[CH / 256], sl[CH / 256];
#pragma unroll
    for (int k = 0; k < CH / 256; ++k) {
        int i = t + k * 256;
        if (i < cnt) {
            dl[k] = dst[base + i];
            sl[k] = src[base + i];
            atomicAdd(&hd[dl[k] >> 9], 1);
            atomicAdd(&hs[sl[k] >> 9], 1);
        }
    }
    __syncthreads();
    // inclusive scans of hd, hs
    for (int off = 1; off < nbuk; off <<= 1) {
        int v0 = (t >= off && t < nbuk) ? hd[t - off] : 0;
        int w0 = (t >= off && t < nbuk) ? hs[t - off] : 0;
        __syncthreads();
        if (t < nbuk) { hd[t] += v0; hs[t] += w0; }
        __syncthreads();
    }
    if (t < nbuk) {
        int excD = t ? hd[t - 1] : 0;
        int excS = t ? hs[t - 1] : 0;
        curD[t] = excD;
        curS[t] = excS;
        baseD[t] = scan[t * B1 + blockIdx.x] - excD;
        baseS[t] = scan[(nbuk + t) * B1 + blockIdx.x] - excS;
    }
    __syncthreads();
#pragma unroll
    for (int k = 0; k < CH / 256; ++k) {
        int i = t + k * 256;
        if (i < cnt) {
            int j = dl[k] >> 9;
            int p = atomicAdd(&curD[j], 1);
            stD_d[p] = dl[k];
            stD_s[p] = sl[k];
            int jq = sl[k] >> 9;
            int q = atomicAdd(&curS[jq], 1);
            stS_s[q] = sl[k];
        }
    }
    __syncthreads();
    // copy out: consecutive sorted positions -> near-coalesced run writes
    for (int i = t; i < cnt; i += 256) {
        int lo = 0, hi = nbuk - 1;                 // smallest j with hd[j] > i
        while (lo < hi) { int mid = (lo + hi) >> 1; if (hd[mid] > i) hi = mid; else lo = mid + 1; }
        int gd = baseD[lo] + i;
        pd[gd] = stD_d[i];
        psqs[gd] = stD_s[i];
        int lo2 = 0, hi2 = nbuk - 1;
        while (lo2 < hi2) { int mid = (lo2 + hi2) >> 1; if (hs[mid] > i) hi2 = mid; else lo2 = mid + 1; }
        psqs[baseS[lo2] + i] = stS_s[i];
    }
}

// ---------------- P2: per-bucket local sort -> esrc (coalesced), seg, norm_dst ----------------
__global__ __launch_bounds__(256) void p2_kernel(const int* __restrict__ pd, const int* __restrict__ ps,
                                                 const int* __restrict__ scan,
                                                 int* __restrict__ esrc, int* __restrict__ seg,
                                                 float* __restrict__ norm_dst,
                                                 int N, int E, int B1) {
    __shared__ int h[512];      // inclusive after scan
    __shared__ int cur[512];
    __shared__ int stage[MAXB];
    const int t = threadIdx.x;
    const int b = blockIdx.x;
    h[t] = 0; h[t + 256] = 0;
    __syncthreads();
    const int bb0 = scan[b * B1];
    const int bb1 = scan[(b + 1) * B1];   // last bucket reads scan[nbuk*B1] == E
    for (int i = bb0 + t; i < bb1; i += 256) atomicAdd(&h[pd[i] & 511], 1);
    __syncthreads();
    for (int off = 1; off < 512; off <<= 1) {
        int v0 = (t >= off) ? h[t - off] : 0;
        int v1 = (t + 256 >= off) ? h[t + 256 - off] : 0;
        __syncthreads();
        h[t] += v0;
        h[t + 256] += v1;
        __syncthreads();
    }
#pragma unroll
    for (int r = 0; r < 2; ++r) {
        int j = t + r * 256;
        int exc = j ? h[j - 1] : 0;
        cur[j] = exc;
        int n = (b << 9) + j;
        if (n < N) {
            seg[n] = bb0 + exc;
            norm_dst[n] = rsqrtf(fmaxf((float)(h[j] - exc), 1.0f));
        }
    }
    if (b == 0 && t == 0) seg[N] = E;
    __syncthreads();
    const int cnt = bb1 - bb0;
    for (int i = bb0 + t; i < bb1; i += 256) {
        int j = pd[i] & 511;
        int p = atomicAdd(&cur[j], 1);
        int s = ps[i];
        if (p < MAXB) stage[p] = s; else esrc[bb0 + p] = s;
    }
    __syncthreads();
    for (int i = t; i < cnt && i < MAXB; i += 256) esrc[bb0 + i] = stage[i];
}

// ---------------- S2: per-bucket src histogram -> norm_src ----------------
__global__ __launch_bounds__(256) void s2_kernel(const int* __restrict__ psqs, const int* __restrict__ scan,
                                                 float* __restrict__ norm_src, int N, int B1, int nbuk) {
    __shared__ int h[512];
    const int t = threadIdx.x;
    const int b = blockIdx.x;
    h[t] = 0; h[t + 256] = 0;
    __syncthreads();
    const int sb0 = scan[(nbuk + b) * B1];
    const int sb1 = scan[(nbuk + b + 1) * B1];  // last bucket reads scan[M] == 2E
    for (int i = sb0 + t; i < sb1; i += 256) atomicAdd(&h[psqs[i] & 511], 1);
    __syncthreads();
#pragma unroll
    for (int r = 0; r < 2; ++r) {
        int j = t + r * 256;
        int n = (b << 9) + j;
        if (n < N) norm_src[n] = rsqrtf(fmaxf((float)h[j], 1.0f));
    }
}

// ---------------- X = (H @ W) * norm_row ----------------
template<int K>
__global__ __launch_bounds__(256) void gemm_norm(const float* __restrict__ H,
                                                 const float* __restrict__ W,
                                                 const float* __restrict__ norm,
                                                 float* __restrict__ X, int N) {
    constexpr int KSHIFT = (K == 128) ? 7 : 6;
    __shared__ __align__(16) float sHT[K * 68];
    __shared__ __align__(16) float sW[K * 64];
    const int tid = threadIdx.x;
    const int n0 = blockIdx.x * 64;

    for (int i = tid; i < K * 64; i += 256) sW[i] = W[i];
    for (int i = tid; i < 64 * K; i += 256) {
        int n = i >> KSHIFT;
        int k = i & (K - 1);
        float v = (n0 + n < N) ? H[(size_t)(n0 + n) * K + k] : 0.0f;
        sHT[k * 68 + n] = v;
    }
    __syncthreads();

    const int tx = tid & 15;
    const int ty = tid >> 4;
    float acc[4][4];
#pragma unroll
    for (int i = 0; i < 4; ++i)
#pragma unroll
        for (int m = 0; m < 4; ++m) acc[i][m] = 0.0f;

#pragma unroll 4
    for (int k = 0; k < K; ++k) {
        const float4 hv = *(const float4*)&sHT[k * 68 + 4 * ty];
        const float4 wv = *(const float4*)&sW[k * 64 + 4 * tx];
        acc[0][0] += hv.x * wv.x; acc[0][1] += hv.x * wv.y; acc[0][2] += hv.x * wv.z; acc[0][3] += hv.x * wv.w;
        acc[1][0] += hv.y * wv.x; acc[1][1] += hv.y * wv.y; acc[1][2] += hv.y * wv.z; acc[1][3] += hv.y * wv.w;
        acc[2][0] += hv.z * wv.x; acc[2][1] += hv.z * wv.y; acc[2][2] += hv.z * wv.z; acc[2][3] += hv.z * wv.w;
        acc[3][0] += hv.w * wv.x; acc[3][1] += hv.w * wv.y; acc[3][2] += hv.w * wv.z; acc[3][3] += hv.w * wv.w;
    }

#pragma unroll
    for (int i = 0; i < 4; ++i) {
        int n = n0 + 4 * ty + i;
        if (n < N) {
            float s = norm[n];
            float4 o;
            o.x = acc[i][0] * s; o.y = acc[i][1] * s; o.z = acc[i][2] * s; o.w = acc[i][3] * s;
            *(float4*)&X[(size_t)n * 64 + 4 * tx] = o;
        }
    }
}

// ---------------- segment sum over CSR + fused epilogue ----------------
template<bool ELU>
__global__ __launch_bounds__(256) void segsum_kernel(const float* __restrict__ X,
                                                     const int* __restrict__ esrc,
                                                     const int* __restrict__ seg,
                                                     const float* __restrict__ norm_dst,
                                                     const float* __restrict__ b,
                                                     float* __restrict__ out, int N) {
    const int node = blockIdx.x * 4 + (threadIdx.x >> 6);
    const int lane = threadIdx.x & 63;
    if (node >= N) return;
    const int s0 = seg[node];
    const int s1 = seg[node + 1];
    float acc = 0.0f;
    int e = s0;
    for (; e + 4 <= s1; e += 4) {
        int a0 = esrc[e + 0];
        int a1 = esrc[e + 1];
        int a2 = esrc[e + 2];
        int a3 = esrc[e + 3];
        acc += X[(size_t)a0 * 64 + lane];
        acc += X[(size_t)a1 * 64 + lane];
        acc += X[(size_t)a2 * 64 + lane];
        acc += X[(size_t)a3 * 64 + lane];
    }
    for (; e < s1; ++e) acc += X[(size_t)esrc[e] * 64 + lane];
    float r = acc * norm_dst[node] + b[lane];
    if (ELU) r = (r > 0.0f) ? r : expm1f(r);
    out[(size_t)node * 64 + lane] = r;
}

extern "C" void kernel_launch(void* const* d_in, const int* in_sizes, int n_in,
                              void* d_out, int out_size, void* d_ws, size_t ws_size,
                              hipStream_t stream) {
    const float* h   = (const float*)d_in[0];
    const int*   src = (const int*)d_in[1];
    const int*   dst = (const int*)d_in[2];
    const float* W1  = (const float*)d_in[3];
    const float* b1  = (const float*)d_in[4];
    const float* W2  = (const float*)d_in[5];
    const float* b2  = (const float*)d_in[6];
    float* out = (float*)d_out;

    const int N = in_sizes[0] / 128;       // 100000
    const int E = in_sizes[1];             // 1600000
    const int nbuk = (N + 511) >> 9;       // 196
    const int B1 = (E + CH - 1) / CH;      // 391
    const int M = 2 * nbuk * B1;           // 153272

    // ---- workspace layout (all int-aligned, floats after) ----
    int* iw = (int*)d_ws;
    int* mat   = iw;                         // M
    int* scanb = mat + M;                    // M + 1 (+pad 3)
    int* bsums = scanb + M + 4;              // 256
    int* pd    = bsums + 256;                // E
    int* psqs  = pd + (size_t)E;             // 2E
    int* esrc  = psqs + 2 * (size_t)E;       // E
    int* seg   = esrc + (size_t)E;           // N+1 (+pad 3)
    float* fw       = (float*)(seg + (size_t)N + 4);
    float* norm_src = fw;
    float* norm_dst = fw + (size_t)N;
    float* X        = fw + 2 * (size_t)N;
    float* H1       = X + 64 * (size_t)N;

    // ---- CSR build: bucket-partition radix (no global atomics) ----
    p1a_kernel<<<B1, 256, 0, stream>>>(src, dst, mat, E, B1, nbuk);
    const int G = (M + 1023) / 1024;       // 150 <= 256
    scan1_kernel<<<G, 256, 0, stream>>>(mat, scanb, bsums, M);
    scan2_kernel<<<1, 256, 0, stream>>>(bsums, scanb, M, G);
    scan3_kernel<<<G, 256, 0, stream>>>(scanb, bsums, M);
    p1c_kernel<<<B1, 256, 0, stream>>>(src, dst, scanb, pd, psqs, E, B1, nbuk);
    p2_kernel<<<nbuk, 256, 0, stream>>>(pd, psqs, scanb, esrc, seg, norm_dst, N, E, B1);
    s2_kernel<<<nbuk, 256, 0, stream>>>(psqs, scanb, norm_src, N, B1, nbuk);

    // ---- layer 1 ----
    gemm_norm<128><<<(N + 63) / 64, 256, 0, stream>>>(h, W1, norm_src, X, N);
    segsum_kernel<true><<<(N + 3) / 4, 256, 0, stream>>>(X, esrc, seg, norm_dst, b1, H1, N);

    // ---- layer 2 ----
    gemm_norm<64><<<(N + 63) / 64, 256, 0, stream>>>(H1, W2, norm_src, X, N);
    segsum_kernel<false><<<(N + 3) / 4, 256, 0, stream>>>(X, esrc, seg, norm_dst, b2, out, N);
}

// Round 4
// 389.280 us; speedup vs baseline: 7.9501x; 1.1404x over previous
//
#include <hip/hip_runtime.h>
#include <math.h>

#define CH 4096        // edges per partition block
#define NBUK_MAX 256   // max buckets (N <= 131072)
#define MAXB 12288     // max edges per bucket staged in LDS (48 KB)

// ---------------- P1a: per-block bucket histograms (dst-bucket and src-bucket) ----------------
__global__ __launch_bounds__(256) void p1a_kernel(const int* __restrict__ src, const int* __restrict__ dst,
                                                  int* __restrict__ mat, int E, int B1, int nbuk) {
    __shared__ int hd[NBUK_MAX], hs[NBUK_MAX];
    const int t = threadIdx.x;
    if (t < nbuk) { hd[t] = 0; hs[t] = 0; }
    __syncthreads();
    const int base = blockIdx.x * CH;
    const int cnt = min(CH, E - base);
    for (int k = t; k < cnt; k += 256) {
        int d = dst[base + k];
        int s = src[base + k];
        atomicAdd(&hd[d >> 9], 1);
        atomicAdd(&hs[s >> 9], 1);
    }
    __syncthreads();
    if (t < nbuk) {
        mat[t * B1 + blockIdx.x] = hd[t];
        mat[(nbuk + t) * B1 + blockIdx.x] = hs[t];
    }
}

// ---------------- 3-phase exclusive scan ----------------
__global__ __launch_bounds__(256) void scan1_kernel(const int* __restrict__ cnt,
                                                    int* __restrict__ seg,
                                                    int* __restrict__ bsums, int N) {
    __shared__ int tsum[256];
    const int t = threadIdx.x;
    const int base = blockIdx.x * 1024 + t * 4;
    int v0 = (base + 0 < N) ? cnt[base + 0] : 0;
    int v1 = (base + 1 < N) ? cnt[base + 1] : 0;
    int v2 = (base + 2 < N) ? cnt[base + 2] : 0;
    int v3 = (base + 3 < N) ? cnt[base + 3] : 0;
    tsum[t] = v0 + v1 + v2 + v3;
    __syncthreads();
    for (int off = 1; off < 256; off <<= 1) {
        int x = (t >= off) ? tsum[t - off] : 0;
        __syncthreads();
        if (t >= off) tsum[t] += x;
        __syncthreads();
    }
    int run = (t > 0) ? tsum[t - 1] : 0;
    if (base + 0 < N) seg[base + 0] = run; run += v0;
    if (base + 1 < N) seg[base + 1] = run; run += v1;
    if (base + 2 < N) seg[base + 2] = run; run += v2;
    if (base + 3 < N) seg[base + 3] = run;
    if (t == 255) bsums[blockIdx.x] = tsum[255];
}

__global__ void scan2_kernel(int* __restrict__ bsums, int* __restrict__ seg, int N, int G) {
    __shared__ int s[256];
    int t = threadIdx.x;
    if (t < G) s[t] = bsums[t];
    __syncthreads();
    if (t == 0) {
        int run = 0;
        for (int i = 0; i < G; ++i) { int v = s[i]; s[i] = run; run += v; }
        seg[N] = run;
    }
    __syncthreads();
    if (t < G) bsums[t] = s[t];
}

__global__ __launch_bounds__(256) void scan3_kernel(int* __restrict__ seg,
                                                    const int* __restrict__ bsums, int N) {
    int add = bsums[blockIdx.x];
    int base = blockIdx.x * 1024 + threadIdx.x * 4;
#pragma unroll
    for (int i = 0; i < 4; ++i) {
        int idx = base + i;
        if (idx < N) seg[idx] += add;
    }
}

// ---------------- P1c: LDS-staged partition scatter ----------------
__global__ __launch_bounds__(256) void p1c_kernel(const int* __restrict__ src, const int* __restrict__ dst,
                                                  const int* __restrict__ scan,
                                                  int* __restrict__ pd, int* __restrict__ psqs,
                                                  int E, int B1, int nbuk) {
    __shared__ int hd[NBUK_MAX], hs[NBUK_MAX];
    __shared__ int curD[NBUK_MAX], curS[NBUK_MAX];
    __shared__ int baseD[NBUK_MAX], baseS[NBUK_MAX];
    __shared__ int stD_d[CH];
    __shared__ int stD_s[CH];
    __shared__ int stS_s[CH];
    const int t = threadIdx.x;
    if (t < nbuk) { hd[t] = 0; hs[t] = 0; }
    __syncthreads();
    const int base = blockIdx.x * CH;
    const int cnt = min(CH, E - base);
    int dl[CH / 256], sl[CH / 256];
#pragma unroll
    for (int k = 0; k < CH / 256; ++k) {
        int i = t + k * 256;
        if (i < cnt) {
            dl[k] = dst[base + i];
            sl[k] = src[base + i];
            atomicAdd(&hd[dl[k] >> 9], 1);
            atomicAdd(&hs[sl[k] >> 9], 1);
        }
    }
    __syncthreads();
    for (int off = 1; off < nbuk; off <<= 1) {
        int v0 = (t >= off && t < nbuk) ? hd[t - off] : 0;
        int w0 = (t >= off && t < nbuk) ? hs[t - off] : 0;
        __syncthreads();
        if (t < nbuk) { hd[t] += v0; hs[t] += w0; }
        __syncthreads();
    }
    if (t < nbuk) {
        int excD = t ? hd[t - 1] : 0;
        int excS = t ? hs[t - 1] : 0;
        curD[t] = excD;
        curS[t] = excS;
        baseD[t] = scan[t * B1 + blockIdx.x] - excD;
        baseS[t] = scan[(nbuk + t) * B1 + blockIdx.x] - excS;
    }
    __syncthreads();
#pragma unroll
    for (int k = 0; k < CH / 256; ++k) {
        int i = t + k * 256;
        if (i < cnt) {
            int j = dl[k] >> 9;
            int p = atomicAdd(&curD[j], 1);
            stD_d[p] = dl[k];
            stD_s[p] = sl[k];
            int jq = sl[k] >> 9;
            int q = atomicAdd(&curS[jq], 1);
            stS_s[q] = sl[k];
        }
    }
    __syncthreads();
    for (int i = t; i < cnt; i += 256) {
        int lo = 0, hi = nbuk - 1;
        while (lo < hi) { int mid = (lo + hi) >> 1; if (hd[mid] > i) hi = mid; else lo = mid + 1; }
        int gd = baseD[lo] + i;
        pd[gd] = stD_d[i];
        psqs[gd] = stD_s[i];
        int lo2 = 0, hi2 = nbuk - 1;
        while (lo2 < hi2) { int mid = (lo2 + hi2) >> 1; if (hs[mid] > i) hi2 = mid; else lo2 = mid + 1; }
        psqs[baseS[lo2] + i] = stS_s[i];
    }
}

// ---------------- P2: per-bucket local sort -> esrc (coalesced), seg, norm_dst ----------------
__global__ __launch_bounds__(256) void p2_kernel(const int* __restrict__ pd, const int* __restrict__ ps,
                                                 const int* __restrict__ scan,
                                                 int* __restrict__ esrc, int* __restrict__ seg,
                                                 float* __restrict__ norm_dst,
                                                 int N, int E, int B1) {
    __shared__ int h[512];
    __shared__ int cur[512];
    __shared__ int stage[MAXB];
    const int t = threadIdx.x;
    const int b = blockIdx.x;
    h[t] = 0; h[t + 256] = 0;
    __syncthreads();
    const int bb0 = scan[b * B1];
    const int bb1 = scan[(b + 1) * B1];
    for (int i = bb0 + t; i < bb1; i += 256) atomicAdd(&h[pd[i] & 511], 1);
    __syncthreads();
    for (int off = 1; off < 512; off <<= 1) {
        int v0 = (t >= off) ? h[t - off] : 0;
        int v1 = (t + 256 >= off) ? h[t + 256 - off] : 0;
        __syncthreads();
        h[t] += v0;
        h[t + 256] += v1;
        __syncthreads();
    }
#pragma unroll
    for (int r = 0; r < 2; ++r) {
        int j = t + r * 256;
        int exc = j ? h[j - 1] : 0;
        cur[j] = exc;
        int n = (b << 9) + j;
        if (n < N) {
            seg[n] = bb0 + exc;
            norm_dst[n] = rsqrtf(fmaxf((float)(h[j] - exc), 1.0f));
        }
    }
    if (b == 0 && t == 0) seg[N] = E;
    __syncthreads();
    const int cnt = bb1 - bb0;
    for (int i = bb0 + t; i < bb1; i += 256) {
        int j = pd[i] & 511;
        int p = atomicAdd(&cur[j], 1);
        int s = ps[i];
        if (p < MAXB) stage[p] = s; else esrc[bb0 + p] = s;
    }
    __syncthreads();
    for (int i = t; i < cnt && i < MAXB; i += 256) esrc[bb0 + i] = stage[i];
}

// ---------------- S2: per-bucket src histogram -> norm_src ----------------
__global__ __launch_bounds__(256) void s2_kernel(const int* __restrict__ psqs, const int* __restrict__ scan,
                                                 float* __restrict__ norm_src, int N, int B1, int nbuk) {
    __shared__ int h[512];
    const int t = threadIdx.x;
    const int b = blockIdx.x;
    h[t] = 0; h[t + 256] = 0;
    __syncthreads();
    const int sb0 = scan[(nbuk + b) * B1];
    const int sb1 = scan[(nbuk + b + 1) * B1];
    for (int i = sb0 + t; i < sb1; i += 256) atomicAdd(&h[psqs[i] & 511], 1);
    __syncthreads();
#pragma unroll
    for (int r = 0; r < 2; ++r) {
        int j = t + r * 256;
        int n = (b << 9) + j;
        if (n < N) norm_src[n] = rsqrtf(fmaxf((float)h[j], 1.0f));
    }
}

// ---------------- X = (H @ W) * norm_row ----------------
// 64 nodes x 64 cols per block; BK=32 K-chunks; thread tile = 4 consecutive
// nodes x 4 cols. LDS 17.4 KB -> 8 blocks/CU. H row-major (stride 36, no
// transpose): hv reads are broadcast ds_read_b128 (conflict-free). Register
// prefetch of next chunk overlaps global latency with compute.
#define FMA4(s, wv, i) acc[i][0] += (s) * wv.x; acc[i][1] += (s) * wv.y; \
                       acc[i][2] += (s) * wv.z; acc[i][3] += (s) * wv.w;
template<int K>
__global__ __launch_bounds__(256) void gemm_norm(const float* __restrict__ H,
                                                 const float* __restrict__ W,
                                                 const float* __restrict__ norm,
                                                 float* __restrict__ X, int N) {
    constexpr int BK = 32;
    constexpr int NCH = K / BK;
    __shared__ __align__(16) float sH[64 * 36];   // [node][k], pad->stride 36
    __shared__ __align__(16) float sW[BK * 64];   // [k][col]
    const int tid = threadIdx.x;
    const int n0 = blockIdx.x * 64;
    const int tx = tid & 15;          // cols 4tx..4tx+3
    const int ty = tid >> 4;          // nodes 4ty..4ty+3

    const int hr = tid >> 3;          // 0..31 (plus +32 second half)
    const int hc = (tid & 7) * 4;     // float4 col within chunk
    const int wk = tid >> 4;          // 0..15 (plus +16)
    const int wc = (tid & 15) * 4;

    float4 hA, hB, wA, wB;
    const float4 zero4 = {0.0f, 0.0f, 0.0f, 0.0f};

    // prefetch chunk 0
    {
        int r0 = n0 + hr, r1 = n0 + hr + 32;
        hA = (r0 < N) ? *(const float4*)&H[(size_t)r0 * K + hc] : zero4;
        hB = (r1 < N) ? *(const float4*)&H[(size_t)r1 * K + hc] : zero4;
        wA = *(const float4*)&W[(size_t)wk * 64 + wc];
        wB = *(const float4*)&W[(size_t)(wk + 16) * 64 + wc];
    }

    float acc[4][4];
#pragma unroll
    for (int i = 0; i < 4; ++i)
#pragma unroll
        for (int m = 0; m < 4; ++m) acc[i][m] = 0.0f;

    for (int c = 0; c < NCH; ++c) {
        __syncthreads();
        *(float4*)&sH[hr * 36 + hc] = hA;
        *(float4*)&sH[(hr + 32) * 36 + hc] = hB;
        *(float4*)&sW[wk * 64 + wc] = wA;
        *(float4*)&sW[(wk + 16) * 64 + wc] = wB;
        __syncthreads();
        if (c + 1 < NCH) {
            int k0 = (c + 1) * BK;
            int r0 = n0 + hr, r1 = n0 + hr + 32;
            hA = (r0 < N) ? *(const float4*)&H[(size_t)r0 * K + k0 + hc] : zero4;
            hB = (r1 < N) ? *(const float4*)&H[(size_t)r1 * K + k0 + hc] : zero4;
            wA = *(const float4*)&W[(size_t)(k0 + wk) * 64 + wc];
            wB = *(const float4*)&W[(size_t)(k0 + wk + 16) * 64 + wc];
        }
#pragma unroll
        for (int kk = 0; kk < BK; kk += 4) {
            const float4 a0 = *(const float4*)&sH[(4 * ty + 0) * 36 + kk];
            const float4 a1 = *(const float4*)&sH[(4 * ty + 1) * 36 + kk];
            const float4 a2 = *(const float4*)&sH[(4 * ty + 2) * 36 + kk];
            const float4 a3 = *(const float4*)&sH[(4 * ty + 3) * 36 + kk];
            const float4 w0 = *(const float4*)&sW[(kk + 0) * 64 + 4 * tx];
            const float4 w1 = *(const float4*)&sW[(kk + 1) * 64 + 4 * tx];
            const float4 w2 = *(const float4*)&sW[(kk + 2) * 64 + 4 * tx];
            const float4 w3 = *(const float4*)&sW[(kk + 3) * 64 + 4 * tx];
            FMA4(a0.x, w0, 0) FMA4(a1.x, w0, 1) FMA4(a2.x, w0, 2) FMA4(a3.x, w0, 3)
            FMA4(a0.y, w1, 0) FMA4(a1.y, w1, 1) FMA4(a2.y, w1, 2) FMA4(a3.y, w1, 3)
            FMA4(a0.z, w2, 0) FMA4(a1.z, w2, 1) FMA4(a2.z, w2, 2) FMA4(a3.z, w2, 3)
            FMA4(a0.w, w3, 0) FMA4(a1.w, w3, 1) FMA4(a2.w, w3, 2) FMA4(a3.w, w3, 3)
        }
    }

#pragma unroll
    for (int i = 0; i < 4; ++i) {
        int n = n0 + 4 * ty + i;
        if (n < N) {
            float s = norm[n];
            float4 o;
            o.x = acc[i][0] * s; o.y = acc[i][1] * s; o.z = acc[i][2] * s; o.w = acc[i][3] * s;
            *(float4*)&X[(size_t)n * 64 + 4 * tx] = o;
        }
    }
}

// ---------------- segment sum over CSR + fused epilogue ----------------
template<bool ELU>
__global__ __launch_bounds__(256) void segsum_kernel(const float* __restrict__ X,
                                                     const int* __restrict__ esrc,
                                                     const int* __restrict__ seg,
                                                     const float* __restrict__ norm_dst,
                                                     const float* __restrict__ b,
                                                     float* __restrict__ out, int N) {
    const int node = blockIdx.x * 4 + (threadIdx.x >> 6);
    const int lane = threadIdx.x & 63;
    if (node >= N) return;
    const int s0 = seg[node];
    const int s1 = seg[node + 1];
    float acc = 0.0f;
    int e = s0;
    for (; e + 4 <= s1; e += 4) {
        int a0 = esrc[e + 0];
        int a1 = esrc[e + 1];
        int a2 = esrc[e + 2];
        int a3 = esrc[e + 3];
        acc += X[(size_t)a0 * 64 + lane];
        acc += X[(size_t)a1 * 64 + lane];
        acc += X[(size_t)a2 * 64 + lane];
        acc += X[(size_t)a3 * 64 + lane];
    }
    for (; e < s1; ++e) acc += X[(size_t)esrc[e] * 64 + lane];
    float r = acc * norm_dst[node] + b[lane];
    if (ELU) r = (r > 0.0f) ? r : expm1f(r);
    out[(size_t)node * 64 + lane] = r;
}

extern "C" void kernel_launch(void* const* d_in, const int* in_sizes, int n_in,
                              void* d_out, int out_size, void* d_ws, size_t ws_size,
                              hipStream_t stream) {
    const float* h   = (const float*)d_in[0];
    const int*   src = (const int*)d_in[1];
    const int*   dst = (const int*)d_in[2];
    const float* W1  = (const float*)d_in[3];
    const float* b1  = (const float*)d_in[4];
    const float* W2  = (const float*)d_in[5];
    const float* b2  = (const float*)d_in[6];
    float* out = (float*)d_out;

    const int N = in_sizes[0] / 128;       // 100000
    const int E = in_sizes[1];             // 1600000
    const int nbuk = (N + 511) >> 9;       // 196
    const int B1 = (E + CH - 1) / CH;      // 391
    const int M = 2 * nbuk * B1;

    int* iw = (int*)d_ws;
    int* mat   = iw;
    int* scanb = mat + M;
    int* bsums = scanb + M + 4;
    int* pd    = bsums + 256;
    int* psqs  = pd + (size_t)E;
    int* esrc  = psqs + 2 * (size_t)E;
    int* seg   = esrc + (size_t)E;
    float* fw       = (float*)(seg + (size_t)N + 4);
    float* norm_src = fw;
    float* norm_dst = fw + (size_t)N;
    float* X        = fw + 2 * (size_t)N;
    float* H1       = X + 64 * (size_t)N;

    // ---- CSR build ----
    p1a_kernel<<<B1, 256, 0, stream>>>(src, dst, mat, E, B1, nbuk);
    const int G = (M + 1023) / 1024;
    scan1_kernel<<<G, 256, 0, stream>>>(mat, scanb, bsums, M);
    scan2_kernel<<<1, 256, 0, stream>>>(bsums, scanb, M, G);
    scan3_kernel<<<G, 256, 0, stream>>>(scanb, bsums, M);
    p1c_kernel<<<B1, 256, 0, stream>>>(src, dst, scanb, pd, psqs, E, B1, nbuk);
    p2_kernel<<<nbuk, 256, 0, stream>>>(pd, psqs, scanb, esrc, seg, norm_dst, N, E, B1);
    s2_kernel<<<nbuk, 256, 0, stream>>>(psqs, scanb, norm_src, N, B1, nbuk);

    // ---- layer 1 ----
    gemm_norm<128><<<(N + 63) / 64, 256, 0, stream>>>(h, W1, norm_src, X, N);
    segsum_kernel<true><<<(N + 3) / 4, 256, 0, stream>>>(X, esrc, seg, norm_dst, b1, H1, N);

    // ---- layer 2 ----
    gemm_norm<64><<<(N + 63) / 64, 256, 0, stream>>>(H1, W2, norm_src, X, N);
    segsum_kernel<false><<<(N + 3) / 4, 256, 0, stream>>>(X, esrc, seg, norm_dst, b2, out, N);
}